// Round 4
// baseline (259.824 us; speedup 1.0000x reference)
//
#include <hip/hip_runtime.h>
#include <math.h>

namespace {

constexpr int kS = 26;
constexpr int kA = 5;
constexpr int kP = kS * kS * kA;   // 3380
constexpr int kM = 30;
constexpr int kB = 128;
constexpr float kCW = 16.0f;       // IM / S
constexpr int kT = 256;            // threads/block (4 waves)
constexpr int kBoxB = 256;         // boxes per block (1 per thread)
constexpr int kChunks = (kP + kBoxB - 1) / kBoxB;  // 14
constexpr int kGrid = kChunks * kB;                // 1792 blocks

// ws: keys[kB*kM] u64 | accum[3] f32 | counter u32 (memset to 0 each call)
constexpr size_t kKeyBytes = (size_t)kB * kM * 8;  // 30720
constexpr size_t kZeroBytes = kKeyBytes + 16;

__device__ __forceinline__ float sig(float x) { return 1.0f / (1.0f + expf(-x)); }

// ---- DPP wave64 reductions (VALU pipe). Result broadcast via readlane(63). ----
// bound_ctrl=1 injects 0.0 for OOB lane reads: identity for sum, and for max
// over non-negative values (we only consume smax when smax > 0).
template <int C>
__device__ __forceinline__ float dpp_maxf(float v) {
  const int o = __builtin_amdgcn_update_dpp(0, __float_as_int(v), C, 0xF, 0xF, true);
  return fmaxf(v, __int_as_float(o));
}
__device__ __forceinline__ float wave_maxf(float v) {
  v = dpp_maxf<0x111>(v);  // row_shr:1
  v = dpp_maxf<0x112>(v);  // row_shr:2
  v = dpp_maxf<0x114>(v);  // row_shr:4
  v = dpp_maxf<0x118>(v);  // row_shr:8
  v = dpp_maxf<0x142>(v);  // row_bcast:15
  v = dpp_maxf<0x143>(v);  // row_bcast:31
  return __int_as_float(__builtin_amdgcn_readlane(__float_as_int(v), 63));
}
template <int C>
__device__ __forceinline__ float dpp_add(float v) {
  const int o = __builtin_amdgcn_update_dpp(0, __float_as_int(v), C, 0xF, 0xF, true);
  return v + __int_as_float(o);
}
__device__ __forceinline__ float wave_sum(float v) {
  v = dpp_add<0x111>(v);
  v = dpp_add<0x112>(v);
  v = dpp_add<0x114>(v);
  v = dpp_add<0x118>(v);
  v = dpp_add<0x142>(v);
  v = dpp_add<0x143>(v);
  return __int_as_float(__builtin_amdgcn_readlane(__float_as_int(v), 63));
}

__device__ __forceinline__ float rl_f(float v, int m) {
  return __int_as_float(__builtin_amdgcn_readlane(__float_as_int(v), m));
}

__global__ __launch_bounds__(kT) void yolo_loss(
    const float* __restrict__ pred, const float* __restrict__ targ,
    const float* __restrict__ anch, float* __restrict__ out,
    unsigned long long* __restrict__ keys, float* __restrict__ accum,
    unsigned* __restrict__ counter) {
  // 25.6 KB stage buffer, reused by the finale for idx/valid arrays.
  __shared__ __align__(16) char s_mem[kBoxB * 25 * 4];
  __shared__ float s_traw[kM * 5];
  __shared__ float s_anc[2 * kA];
  __shared__ unsigned long long s_wkey[kM * 4];
  __shared__ float s_red[4][3];
  __shared__ unsigned s_ticket;

  const int tid = threadIdx.x;
  const int lane = tid & 63;
  const int wid = tid >> 6;
  const int c = blockIdx.x;
  const int b = blockIdx.y;

  const int nbox = min(kBoxB, kP - c * kBoxB);  // 256, or 52 for c==13
  const int n4 = nbox * 25 / 4;                 // 1600 or 325 (both exact)

  if (tid < 2 * kA) s_anc[tid] = anch[tid];
  if (tid < kM * 5) s_traw[tid] = targ[b * kM * 5 + tid];
  {
    // fully coalesced float4 stream of this block's box records into LDS;
    // base byte offset = b*338000 + c*25600, both multiples of 16.
    const float4* src = (const float4*)(pred + ((size_t)b * kP + (size_t)c * kBoxB) * 25);
    float4* dst = (float4*)s_mem;
    for (int i = tid; i < n4; i += kT) dst[i] = src[i];
  }
  __syncthreads();

  // GT params in registers of lanes 0..29 of EVERY wave (readlane-broadcast later)
  float lx1 = 0.f, lx2 = 0.f, ly1 = 0.f, ly2 = 0.f, lga = 0.f;
  int lval = 0;
  if (lane < kM) {
    const float t0 = s_traw[lane * 5 + 0];
    const float t1 = s_traw[lane * 5 + 1];
    const float t2 = s_traw[lane * 5 + 2];
    const float t3 = s_traw[lane * 5 + 3];
    const float t4 = s_traw[lane * 5 + 4];
    const float gxc = t0 + t2 * 0.5f;
    const float gyc = t1 + t3 * 0.5f;
    const float gw = t2 - t0;  // faithful to source
    const float gh = t3 * t1;  // faithful to source
    lx1 = gxc - gw * 0.5f;
    lx2 = gxc + gw * 0.5f;
    ly1 = gyc - gh * 0.5f;
    ly2 = gyc + gh * 0.5f;
    lga = gw * gh;
    lval = (t4 == 1.0f) ? 1 : 0;
  }

  // ---- decode this thread's single box from LDS (scalar regs, no arrays) ----
  const float* stage = (const float*)s_mem;
  const int p = c * kBoxB + tid;
  const bool active = (tid < nbox);
  float px1, px2, py1, py2, ap, cc;
  if (active) {
    const float* pp = stage + tid * 25;
    const float s0 = sig(pp[0]);
    const float s1 = sig(pp[1]);
    const float s2 = sig(pp[2]) * 0.5f;
    const float s3 = sig(pp[3]) * 0.5f;
    cc = sig(pp[4]);
    const int a = p % kA;
    const int gx = (p / kA) % kS;
    const int gy = p / (kA * kS);
    const float bx = (s0 + (float)gx) * kCW;
    const float by = (s1 + (float)gy) * kCW;
    const float bw = expf(s2) * s_anc[2 * a + 0] * kCW;
    const float bh = expf(s3) * s_anc[2 * a + 1] * kCW;
    px1 = bx - bw * 0.5f;  // exactly pbox[...,0] -+ pbox[...,2]/2
    px2 = bx + bw * 0.5f;
    py1 = by - bh * 0.5f;
    py2 = by + bh * 0.5f;
    ap = bw * bh;
  } else {
    // degenerate box: inter=0 -> iou=+-0; can never win a smax>0 ballot
    px1 = INFINITY; px2 = -INFINITY;
    py1 = INFINITY; py2 = -INFINITY;
    ap = 0.0f; cc = 0.0f;
  }

  // ---- m-loop: IoU + f32 DPP wave-max + winner-lane extraction ----
  bool obj = false;
  for (int m = 0; m < kM; ++m) {
    if (!__builtin_amdgcn_readlane(lval, m)) continue;  // wave-uniform
    const float gx1 = rl_f(lx1, m), gx2 = rl_f(lx2, m);
    const float gy1 = rl_f(ly1, m), gy2 = rl_f(ly2, m);
    const float ga = rl_f(lga, m);
    float dx = fminf(gx2, px2) - fmaxf(gx1, px1);
    float dy = fminf(gy2, py2) - fmaxf(gy1, py1);
    dx = fmaxf(dx, 0.0f);
    dy = fmaxf(dy, 0.0f);
    const float inter = dx * dy;
    const float iou = inter / (ga + ap - inter + 1e-9f);
    obj = obj || (iou > 0.6f);
    const float smax = wave_maxf(iou);
    unsigned long long key = 0ull;
    if (smax > 0.0f) {  // wave-uniform
      const unsigned long long ball = __ballot(iou == smax);
      const int wl = (int)(__ffsll(ball) - 1);               // lowest lane = smallest p
      const int wp = __builtin_amdgcn_readlane(p, wl);
      key = (((unsigned long long)(__float_as_uint(smax) | 0x80000000u)) << 32) |
            (unsigned long long)(0xFFFFFFFFu - (unsigned)wp);
    }
    if (lane == 0) s_wkey[m * 4 + wid] = key;
  }

  // ---- conf terms ----
  float objt, noob;
  if (obj) {
    const float d = cc - 1.0f;
    objt = d * d; noob = 0.0f;
  } else {
    objt = 0.0f; noob = cc * cc;
  }
  const float w0 = wave_sum(objt);
  const float w1 = wave_sum(noob);
  if (lane == 0) { s_red[wid][0] = w0; s_red[wid][1] = w1; }
  __syncthreads();

  if (tid < kM && lval) {  // tid<30 => wave 0, lane==tid holds lval
    unsigned long long k = s_wkey[tid * 4 + 0];
    const unsigned long long k1 = s_wkey[tid * 4 + 1];
    const unsigned long long k2 = s_wkey[tid * 4 + 2];
    const unsigned long long k3 = s_wkey[tid * 4 + 3];
    if (k1 > k) k = k1;
    if (k2 > k) k = k2;
    if (k3 > k) k = k3;
    if (k) atomicMax(&keys[(size_t)b * kM + tid], k);
  }
  if (tid == 0) {
    atomicAdd(&accum[0], s_red[0][0] + s_red[1][0] + s_red[2][0] + s_red[3][0]);
    atomicAdd(&accum[1], s_red[0][1] + s_red[1][1] + s_red[2][1] + s_red[3][1]);
  }

  // ---- last-block ticket ----
  __threadfence();
  __syncthreads();
  if (tid == 0) s_ticket = atomicAdd(counter, 1u);
  __syncthreads();
  if (s_ticket != (unsigned)(kGrid - 1)) return;
  __threadfence();

  // ---- finale: loc loss + combine (stage buffer reused) ----
  int* fidx = (int*)s_mem;
  unsigned char* fvf = (unsigned char*)(s_mem + (size_t)kB * kM * 4);

  for (int i = tid; i < kB * kM; i += kT) {
    const unsigned long long k = atomicMax(&keys[i], 0ull);  // coherent read
    fidx[i] = (k == 0ull) ? 0 : (int)(0xFFFFFFFFu - (unsigned)(k & 0xFFFFFFFFull));
    const int bb = i / kM;
    const int mm = i - bb * kM;
    fvf[i] = (targ[(size_t)bb * kM * 5 + mm * 5 + 4] == 1.0f) ? 1 : 0;
  }
  __syncthreads();

  float loc = 0.0f;
  for (int i = tid; i < kB * kM; i += kT) {
    if (!fvf[i]) continue;
    const int bb = i / kM;
    const int mm = i - bb * kM;
    const int idx = fidx[i];
    bool dead = false;  // last-valid-m-wins dedup (scatter overwrite order)
    for (int j = mm + 1; j < kM; ++j) {
      if (fvf[bb * kM + j] && fidx[bb * kM + j] == idx) { dead = true; break; }
    }
    if (dead) continue;
    const float* tt = targ + (size_t)bb * kM * 5 + mm * 5;
    const float t0 = tt[0], t1 = tt[1], t2 = tt[2], t3 = tt[3];
    const float gxc = t0 + t2 * 0.5f;
    const float gyc = t1 + t3 * 0.5f;
    const int ra = idx % kA;
    const int rw = (idx / kA) % kS;
    const int rh = idx / (kA * kS);
    const float tx = (gxc - (float)rw * kCW) / kCW;
    const float ty = (gyc - (float)rh * kCW) / kCW;
    const float tw = logf((t2 / kCW) / s_anc[2 * ra + 0]);
    const float th = logf((t3 / kCW) / s_anc[2 * ra + 1]);
    const float* pp = pred + ((size_t)bb * kP + idx) * 25;
    const float d0 = sig(pp[0]) - tx;
    const float d1 = sig(pp[1]) - ty;
    const float d2 = sig(pp[2]) * 0.5f - tw;
    const float d3 = sig(pp[3]) * 0.5f - th;
    loc += d0 * d0 + d1 * d1 + d2 * d2 + d3 * d3;
  }
  loc = wave_sum(loc);
  if (lane == 0) s_red[wid][2] = loc;
  __syncthreads();
  if (tid == 0) {
    const float l = s_red[0][2] + s_red[1][2] + s_red[2][2] + s_red[3][2];
    const float a0 = atomicAdd(&accum[0], 0.0f);  // coherent read
    const float a1 = atomicAdd(&accum[1], 0.0f);
    const float loss_conf = (a0 + 0.5f * a1) / (float)kB;
    const float loss_loc = 5.0f * l / (float)kB;
    out[0] = loss_loc + loss_conf;
    out[1] = loss_loc;
    out[2] = loss_conf;
  }
}

}  // namespace

extern "C" void kernel_launch(void* const* d_in, const int* in_sizes, int n_in,
                              void* d_out, int out_size, void* d_ws, size_t ws_size,
                              hipStream_t stream) {
  const float* pred = (const float*)d_in[0];
  const float* targ = (const float*)d_in[1];
  const float* anch = (const float*)d_in[2];
  float* out = (float*)d_out;
  unsigned long long* keys = (unsigned long long*)d_ws;
  float* accum = (float*)((char*)d_ws + kKeyBytes);
  unsigned* counter = (unsigned*)((char*)d_ws + kKeyBytes + 12);

  hipMemsetAsync(d_ws, 0, kZeroBytes, stream);
  yolo_loss<<<dim3(kChunks, kB), kT, 0, stream>>>(pred, targ, anch, out, keys, accum, counter);
}

// Round 5
// 138.770 us; speedup vs baseline: 1.8723x; 1.8723x over previous
//
#include <hip/hip_runtime.h>
#include <math.h>

namespace {

constexpr int kS = 26;
constexpr int kA = 5;
constexpr int kP = kS * kS * kA;   // 3380
constexpr int kM = 30;
constexpr int kB = 128;
constexpr float kCW = 16.0f;       // IM / S
constexpr int kT = 256;            // threads/block (4 waves)
constexpr int kBoxB = 256;         // boxes per block (1 per thread)
constexpr int kChunks = (kP + kBoxB - 1) / kBoxB;  // 14

// ws: keys[kB*kM] u64 | accum[3] f32 (memset to 0 each call)
constexpr size_t kKeyBytes = (size_t)kB * kM * 8;  // 30720
constexpr size_t kZeroBytes = kKeyBytes + 16;

__device__ __forceinline__ float sig(float x) { return 1.0f / (1.0f + expf(-x)); }

// ---- DPP wave64 reductions (VALU pipe). Result broadcast via readlane(63). ----
// bound_ctrl=1 injects 0.0 for OOB lane reads: identity for sum, and for max
// over non-negative values (we only consume smax when smax > 0).
template <int C>
__device__ __forceinline__ float dpp_maxf(float v) {
  const int o = __builtin_amdgcn_update_dpp(0, __float_as_int(v), C, 0xF, 0xF, true);
  return fmaxf(v, __int_as_float(o));
}
__device__ __forceinline__ float wave_maxf(float v) {
  v = dpp_maxf<0x111>(v);  // row_shr:1
  v = dpp_maxf<0x112>(v);  // row_shr:2
  v = dpp_maxf<0x114>(v);  // row_shr:4
  v = dpp_maxf<0x118>(v);  // row_shr:8
  v = dpp_maxf<0x142>(v);  // row_bcast:15
  v = dpp_maxf<0x143>(v);  // row_bcast:31
  return __int_as_float(__builtin_amdgcn_readlane(__float_as_int(v), 63));
}
template <int C>
__device__ __forceinline__ float dpp_add(float v) {
  const int o = __builtin_amdgcn_update_dpp(0, __float_as_int(v), C, 0xF, 0xF, true);
  return v + __int_as_float(o);
}
__device__ __forceinline__ float wave_sum(float v) {
  v = dpp_add<0x111>(v);
  v = dpp_add<0x112>(v);
  v = dpp_add<0x114>(v);
  v = dpp_add<0x118>(v);
  v = dpp_add<0x142>(v);
  v = dpp_add<0x143>(v);
  return __int_as_float(__builtin_amdgcn_readlane(__float_as_int(v), 63));
}

__device__ __forceinline__ float rl_f(float v, int m) {
  return __int_as_float(__builtin_amdgcn_readlane(__float_as_int(v), m));
}

// ============ main: decode + IoU + obj/noobj conf terms + argmax keys ============
__global__ __launch_bounds__(kT) void yolo_main(
    const float* __restrict__ pred, const float* __restrict__ targ,
    const float* __restrict__ anch,
    unsigned long long* __restrict__ keys, float* __restrict__ accum) {
  __shared__ __align__(16) float s_stage[kBoxB * 25];  // 25.6 KB coalesced stage
  __shared__ float s_traw[kM * 5];
  __shared__ float s_anc[2 * kA];
  __shared__ unsigned long long s_wkey[kM * 4];
  __shared__ float s_red[4][2];

  const int tid = threadIdx.x;
  const int lane = tid & 63;
  const int wid = tid >> 6;
  const int c = blockIdx.x;
  const int b = blockIdx.y;

  const int nbox = min(kBoxB, kP - c * kBoxB);  // 256, or 52 for c==13
  const int n4 = nbox * 25 / 4;                 // 1600 or 325 (both exact)

  if (tid < 2 * kA) s_anc[tid] = anch[tid];
  if (tid < kM * 5) s_traw[tid] = targ[b * kM * 5 + tid];
  if (tid < kM * 4) s_wkey[tid] = 0ull;  // screen may skip writes below
  {
    // fully coalesced float4 stream of this block's box records into LDS;
    // base byte offset = b*338000 + c*25600, both multiples of 16.
    const float4* src = (const float4*)(pred + ((size_t)b * kP + (size_t)c * kBoxB) * 25);
    float4* dst = (float4*)s_stage;
    for (int i = tid; i < n4; i += kT) dst[i] = src[i];
  }
  __syncthreads();

  // GT params in registers of lanes 0..29 of EVERY wave (readlane-broadcast later)
  float lx1 = 0.f, lx2 = 0.f, ly1 = 0.f, ly2 = 0.f, lga = 0.f;
  int lval = 0;
  if (lane < kM) {
    const float t0 = s_traw[lane * 5 + 0];
    const float t1 = s_traw[lane * 5 + 1];
    const float t2 = s_traw[lane * 5 + 2];
    const float t3 = s_traw[lane * 5 + 3];
    const float t4 = s_traw[lane * 5 + 4];
    const float gxc = t0 + t2 * 0.5f;
    const float gyc = t1 + t3 * 0.5f;
    const float gw = t2 - t0;  // faithful to source
    const float gh = t3 * t1;  // faithful to source
    lx1 = gxc - gw * 0.5f;
    lx2 = gxc + gw * 0.5f;
    ly1 = gyc - gh * 0.5f;
    ly2 = gyc + gh * 0.5f;
    lga = gw * gh;
    lval = (t4 == 1.0f) ? 1 : 0;
  }

  // ---- decode this thread's single box from LDS (scalar regs, no arrays) ----
  const int p = c * kBoxB + tid;
  const bool active = (tid < nbox);
  float px1, px2, py1, py2, ap, cc;
  if (active) {
    const float* pp = s_stage + tid * 25;
    const float s0 = sig(pp[0]);
    const float s1 = sig(pp[1]);
    const float s2 = sig(pp[2]) * 0.5f;
    const float s3 = sig(pp[3]) * 0.5f;
    cc = sig(pp[4]);
    const int a = p % kA;
    const int gx = (p / kA) % kS;
    const int gy = p / (kA * kS);
    const float bx = (s0 + (float)gx) * kCW;
    const float by = (s1 + (float)gy) * kCW;
    const float bw = expf(s2) * s_anc[2 * a + 0] * kCW;
    const float bh = expf(s3) * s_anc[2 * a + 1] * kCW;
    px1 = bx - bw * 0.5f;  // exactly pbox[...,0] -+ pbox[...,2]/2
    px2 = bx + bw * 0.5f;
    py1 = by - bh * 0.5f;
    py2 = by + bh * 0.5f;
    ap = bw * bh;
  } else {
    // degenerate box: inter=0 -> iou=+-0; can never win a smax>0 ballot
    px1 = INFINITY; px2 = -INFINITY;
    py1 = INFINITY; py2 = -INFINITY;
    ap = 0.0f; cc = 0.0f;
  }

  // ---- m-loop: IoU; ballot screen; f32 DPP wave-max + winner extraction ----
  bool obj = false;
  for (int m = 0; m < kM; ++m) {
    if (!__builtin_amdgcn_readlane(lval, m)) continue;  // wave-uniform
    const float gx1 = rl_f(lx1, m), gx2 = rl_f(lx2, m);
    const float gy1 = rl_f(ly1, m), gy2 = rl_f(ly2, m);
    const float ga = rl_f(lga, m);
    float dx = fminf(gx2, px2) - fmaxf(gx1, px1);
    float dy = fminf(gy2, py2) - fmaxf(gy1, py1);
    dx = fmaxf(dx, 0.0f);
    dy = fmaxf(dy, 0.0f);
    const float inter = dx * dy;
    const float iou = inter / (ga + ap - inter + 1e-9f);
    obj = obj || (iou > 0.6f);
    // screen: most (wave,m) pairs have zero overlap -> skip the reduction
    if (__any(iou > 0.0f)) {
      const float smax = wave_maxf(iou);
      const unsigned long long ball = __ballot(iou == smax);
      const int wl = (int)(__ffsll(ball) - 1);               // lowest lane = smallest p
      const int wp = __builtin_amdgcn_readlane(p, wl);
      const unsigned long long key =
          (((unsigned long long)(__float_as_uint(smax) | 0x80000000u)) << 32) |
          (unsigned long long)(0xFFFFFFFFu - (unsigned)wp);
      if (lane == 0) s_wkey[m * 4 + wid] = key;
    }
  }

  // ---- conf terms ----
  float objt, noob;
  if (obj) {
    const float d = cc - 1.0f;
    objt = d * d; noob = 0.0f;
  } else {
    objt = 0.0f; noob = cc * cc;
  }
  const float w0 = wave_sum(objt);
  const float w1 = wave_sum(noob);
  if (lane == 0) { s_red[wid][0] = w0; s_red[wid][1] = w1; }
  __syncthreads();

  if (tid < kM && lval) {  // tid<30 => wave 0, lane==tid holds lval
    unsigned long long k = s_wkey[tid * 4 + 0];
    const unsigned long long k1 = s_wkey[tid * 4 + 1];
    const unsigned long long k2 = s_wkey[tid * 4 + 2];
    const unsigned long long k3 = s_wkey[tid * 4 + 3];
    if (k1 > k) k = k1;
    if (k2 > k) k = k2;
    if (k3 > k) k = k3;
    if (k) atomicMax(&keys[(size_t)b * kM + tid], k);
  }
  if (tid == 0) {
    atomicAdd(&accum[0], s_red[0][0] + s_red[1][0] + s_red[2][0] + s_red[3][0]);
    atomicAdd(&accum[1], s_red[0][1] + s_red[1][1] + s_red[2][1] + s_red[3][1]);
  }
}

// ============ loc loss: one wave per batch, last-valid-m-wins dedup ============
__global__ __launch_bounds__(64) void loss_B(
    const float* __restrict__ pred, const float* __restrict__ targ,
    const float* __restrict__ anch, const unsigned long long* __restrict__ keys,
    float* __restrict__ accum) {
  const int b = blockIdx.x;
  const int m = threadIdx.x;  // one wave; lanes 0..29 carry GTs
  int idx = -1;
  int valid = 0;
  float t0 = 0.f, t1 = 0.f, t2 = 0.f, t3 = 0.f;
  if (m < kM) {
    const unsigned long long k = keys[b * kM + m];
    idx = (k == 0ull) ? 0 : (int)(0xFFFFFFFFu - (unsigned)(k & 0xFFFFFFFFull));
    t0 = targ[b * kM * 5 + m * 5 + 0];
    t1 = targ[b * kM * 5 + m * 5 + 1];
    t2 = targ[b * kM * 5 + m * 5 + 2];
    t3 = targ[b * kM * 5 + m * 5 + 3];
    valid = (targ[b * kM * 5 + m * 5 + 4] == 1.0f) ? 1 : 0;
  }
  // last-valid-m-wins dedup (matches scatter overwrite order)
  bool dead = false;
  for (int j = 1; j < kM; ++j) {
    const int idx2 = __shfl(idx, j);
    const int v2 = __shfl(valid, j);
    if (j > m && v2 && idx2 == idx) dead = true;
  }
  float loc = 0.0f;
  if (m < kM && valid && !dead) {
    const float gxc = t0 + t2 * 0.5f;
    const float gyc = t1 + t3 * 0.5f;
    const int ra = idx % kA;
    const int rw = (idx / kA) % kS;
    const int rh = idx / (kA * kS);
    const float tx = (gxc - (float)rw * kCW) / kCW;
    const float ty = (gyc - (float)rh * kCW) / kCW;
    const float tw = logf((t2 / kCW) / anch[2 * ra + 0]);
    const float th = logf((t3 / kCW) / anch[2 * ra + 1]);
    const float* pp = pred + ((size_t)b * kP + idx) * 25;
    const float d0 = sig(pp[0]) - tx;
    const float d1 = sig(pp[1]) - ty;
    const float d2 = sig(pp[2]) * 0.5f - tw;
    const float d3 = sig(pp[3]) * 0.5f - th;
    loc = d0 * d0 + d1 * d1 + d2 * d2 + d3 * d3;
  }
  loc = wave_sum(loc);
  if (m == 0) atomicAdd(&accum[2], loc);
}

__global__ void loss_C(const float* __restrict__ accum, float* __restrict__ out) {
  if (threadIdx.x == 0) {
    const float loss_conf = (accum[0] + 0.5f * accum[1]) / (float)kB;
    const float loss_loc = 5.0f * accum[2] / (float)kB;
    out[0] = loss_loc + loss_conf;
    out[1] = loss_loc;
    out[2] = loss_conf;
  }
}

}  // namespace

extern "C" void kernel_launch(void* const* d_in, const int* in_sizes, int n_in,
                              void* d_out, int out_size, void* d_ws, size_t ws_size,
                              hipStream_t stream) {
  const float* pred = (const float*)d_in[0];
  const float* targ = (const float*)d_in[1];
  const float* anch = (const float*)d_in[2];
  float* out = (float*)d_out;
  unsigned long long* keys = (unsigned long long*)d_ws;
  float* accum = (float*)((char*)d_ws + kKeyBytes);

  hipMemsetAsync(d_ws, 0, kZeroBytes, stream);
  yolo_main<<<dim3(kChunks, kB), kT, 0, stream>>>(pred, targ, anch, keys, accum);
  loss_B<<<kB, 64, 0, stream>>>(pred, targ, anch, keys, accum);
  loss_C<<<1, 64, 0, stream>>>(accum, out);
}

// Round 6
// 137.412 us; speedup vs baseline: 1.8908x; 1.0099x over previous
//
#include <hip/hip_runtime.h>
#include <math.h>

namespace {

constexpr int kS = 26;
constexpr int kA = 5;
constexpr int kP = kS * kS * kA;   // 3380
constexpr int kM = 30;
constexpr int kB = 128;
constexpr float kCW = 16.0f;       // IM / S
constexpr int kT = 256;            // threads/block (4 waves)
constexpr int kBoxB = 256;         // boxes per block (1 per thread)
constexpr int kChunks = (kP + kBoxB - 1) / kBoxB;  // 14
constexpr int kN4Full = kBoxB * 25 / 4;            // 1600 float4 per full chunk

// ws: keys[kB*kM] u64 | accum[3] f32 (memset to 0 each call)
constexpr size_t kKeyBytes = (size_t)kB * kM * 8;  // 30720
constexpr size_t kZeroBytes = kKeyBytes + 16;

__device__ __forceinline__ float sig(float x) { return 1.0f / (1.0f + expf(-x)); }

// ---- DPP wave64 reductions (VALU pipe). Result broadcast via readlane(63). ----
template <int C>
__device__ __forceinline__ float dpp_maxf(float v) {
  const int o = __builtin_amdgcn_update_dpp(0, __float_as_int(v), C, 0xF, 0xF, true);
  return fmaxf(v, __int_as_float(o));
}
__device__ __forceinline__ float wave_maxf(float v) {
  v = dpp_maxf<0x111>(v);  // row_shr:1
  v = dpp_maxf<0x112>(v);  // row_shr:2
  v = dpp_maxf<0x114>(v);  // row_shr:4
  v = dpp_maxf<0x118>(v);  // row_shr:8
  v = dpp_maxf<0x142>(v);  // row_bcast:15
  v = dpp_maxf<0x143>(v);  // row_bcast:31
  return __int_as_float(__builtin_amdgcn_readlane(__float_as_int(v), 63));
}
template <int C>
__device__ __forceinline__ float dpp_add(float v) {
  const int o = __builtin_amdgcn_update_dpp(0, __float_as_int(v), C, 0xF, 0xF, true);
  return v + __int_as_float(o);
}
__device__ __forceinline__ float wave_sum(float v) {
  v = dpp_add<0x111>(v);
  v = dpp_add<0x112>(v);
  v = dpp_add<0x114>(v);
  v = dpp_add<0x118>(v);
  v = dpp_add<0x142>(v);
  v = dpp_add<0x143>(v);
  return __int_as_float(__builtin_amdgcn_readlane(__float_as_int(v), 63));
}

__device__ __forceinline__ float rl_f(float v, int m) {
  return __int_as_float(__builtin_amdgcn_readlane(__float_as_int(v), m));
}

// ============ main: decode + IoU + obj/noobj conf terms + argmax keys ============
__global__ __launch_bounds__(kT) void yolo_main(
    const float* __restrict__ pred, const float* __restrict__ targ,
    const float* __restrict__ anch,
    unsigned long long* __restrict__ keys, float* __restrict__ accum) {
  __shared__ __align__(16) float s_stage[kBoxB * 25];  // 25.6 KB coalesced stage
  __shared__ float s_traw[kM * 5];
  __shared__ float s_anc[2 * kA];
  __shared__ unsigned long long s_wkey[kM * 4];
  __shared__ float s_red[4][2];

  const int tid = threadIdx.x;
  const int lane = tid & 63;
  const int wid = tid >> 6;
  const int c = blockIdx.x;
  const int b = blockIdx.y;

  const int nbox = min(kBoxB, kP - c * kBoxB);  // 256, or 52 for c==13
  const int n4 = nbox * 25 / 4;                 // 1600 or 325 (both exact)

  if (tid < 2 * kA) s_anc[tid] = anch[tid];
  if (tid < kM * 5) s_traw[tid] = targ[b * kM * 5 + tid];
  if (tid < kM * 4) s_wkey[tid] = 0ull;  // screen may skip writes below
  {
    // MLP-batched coalesced staging: issue ALL independent float4 loads into
    // registers FIRST (112 B/lane in flight), then spill to LDS. The naive
    // load->ds_write loop serializes on vmcnt(0) each iter (R5: 1 load in
    // flight -> ~400 GB/s chip-wide).
    const float4* src = (const float4*)(pred + ((size_t)b * kP + (size_t)c * kBoxB) * 25);
    float4* dst = (float4*)s_stage;
    if (n4 == kN4Full) {
      float4 r[6];
#pragma unroll
      for (int i = 0; i < 6; ++i) r[i] = src[tid + i * kT];  // 1536 <= 1600, all valid
      const bool t6 = tid + 6 * kT < kN4Full;                 // last 64
      float4 r6;
      if (t6) r6 = src[tid + 6 * kT];
#pragma unroll
      for (int i = 0; i < 6; ++i) dst[tid + i * kT] = r[i];
      if (t6) dst[tid + 6 * kT] = r6;
    } else {  // tail chunk c==13 (52 boxes, 325 float4): 2 batched iterations
      float4 r0, r1;
      const bool v0 = tid < n4;
      const bool v1 = tid + kT < n4;
      if (v0) r0 = src[tid];
      if (v1) r1 = src[tid + kT];
      if (v0) dst[tid] = r0;
      if (v1) dst[tid + kT] = r1;
    }
  }
  __syncthreads();

  // GT params in registers of lanes 0..29 of EVERY wave (readlane-broadcast later)
  float lx1 = 0.f, lx2 = 0.f, ly1 = 0.f, ly2 = 0.f, lga = 0.f;
  int lval = 0;
  if (lane < kM) {
    const float t0 = s_traw[lane * 5 + 0];
    const float t1 = s_traw[lane * 5 + 1];
    const float t2 = s_traw[lane * 5 + 2];
    const float t3 = s_traw[lane * 5 + 3];
    const float t4 = s_traw[lane * 5 + 4];
    const float gxc = t0 + t2 * 0.5f;
    const float gyc = t1 + t3 * 0.5f;
    const float gw = t2 - t0;  // faithful to source
    const float gh = t3 * t1;  // faithful to source
    lx1 = gxc - gw * 0.5f;
    lx2 = gxc + gw * 0.5f;
    ly1 = gyc - gh * 0.5f;
    ly2 = gyc + gh * 0.5f;
    lga = gw * gh;
    lval = (t4 == 1.0f) ? 1 : 0;
  }

  // ---- decode this thread's single box from LDS (scalar regs, no arrays) ----
  const int p = c * kBoxB + tid;
  const bool active = (tid < nbox);
  float px1, px2, py1, py2, ap, cc;
  if (active) {
    const float* pp = s_stage + tid * 25;
    const float s0 = sig(pp[0]);
    const float s1 = sig(pp[1]);
    const float s2 = sig(pp[2]) * 0.5f;
    const float s3 = sig(pp[3]) * 0.5f;
    cc = sig(pp[4]);
    const int a = p % kA;
    const int gx = (p / kA) % kS;
    const int gy = p / (kA * kS);
    const float bx = (s0 + (float)gx) * kCW;
    const float by = (s1 + (float)gy) * kCW;
    const float bw = expf(s2) * s_anc[2 * a + 0] * kCW;
    const float bh = expf(s3) * s_anc[2 * a + 1] * kCW;
    px1 = bx - bw * 0.5f;  // exactly pbox[...,0] -+ pbox[...,2]/2
    px2 = bx + bw * 0.5f;
    py1 = by - bh * 0.5f;
    py2 = by + bh * 0.5f;
    ap = bw * bh;
  } else {
    // degenerate box: inter=0 -> iou=+-0; can never win a smax>0 ballot
    px1 = INFINITY; px2 = -INFINITY;
    py1 = INFINITY; py2 = -INFINITY;
    ap = 0.0f; cc = 0.0f;
  }

  // ---- m-loop: IoU; ballot screen; f32 DPP wave-max + winner extraction ----
  bool obj = false;
  for (int m = 0; m < kM; ++m) {
    if (!__builtin_amdgcn_readlane(lval, m)) continue;  // wave-uniform
    const float gx1 = rl_f(lx1, m), gx2 = rl_f(lx2, m);
    const float gy1 = rl_f(ly1, m), gy2 = rl_f(ly2, m);
    const float ga = rl_f(lga, m);
    float dx = fminf(gx2, px2) - fmaxf(gx1, px1);
    float dy = fminf(gy2, py2) - fmaxf(gy1, py1);
    dx = fmaxf(dx, 0.0f);
    dy = fmaxf(dy, 0.0f);
    const float inter = dx * dy;
    const float iou = inter / (ga + ap - inter + 1e-9f);
    obj = obj || (iou > 0.6f);
    // screen: most (wave,m) pairs have zero overlap -> skip the reduction
    if (__any(iou > 0.0f)) {
      const float smax = wave_maxf(iou);
      const unsigned long long ball = __ballot(iou == smax);
      const int wl = (int)(__ffsll(ball) - 1);               // lowest lane = smallest p
      const int wp = __builtin_amdgcn_readlane(p, wl);
      const unsigned long long key =
          (((unsigned long long)(__float_as_uint(smax) | 0x80000000u)) << 32) |
          (unsigned long long)(0xFFFFFFFFu - (unsigned)wp);
      if (lane == 0) s_wkey[m * 4 + wid] = key;
    }
  }

  // ---- conf terms ----
  float objt, noob;
  if (obj) {
    const float d = cc - 1.0f;
    objt = d * d; noob = 0.0f;
  } else {
    objt = 0.0f; noob = cc * cc;
  }
  const float w0 = wave_sum(objt);
  const float w1 = wave_sum(noob);
  if (lane == 0) { s_red[wid][0] = w0; s_red[wid][1] = w1; }
  __syncthreads();

  if (tid < kM && lval) {  // tid<30 => wave 0, lane==tid holds lval
    unsigned long long k = s_wkey[tid * 4 + 0];
    const unsigned long long k1 = s_wkey[tid * 4 + 1];
    const unsigned long long k2 = s_wkey[tid * 4 + 2];
    const unsigned long long k3 = s_wkey[tid * 4 + 3];
    if (k1 > k) k = k1;
    if (k2 > k) k = k2;
    if (k3 > k) k = k3;
    if (k) atomicMax(&keys[(size_t)b * kM + tid], k);
  }
  if (tid == 0) {
    atomicAdd(&accum[0], s_red[0][0] + s_red[1][0] + s_red[2][0] + s_red[3][0]);
    atomicAdd(&accum[1], s_red[0][1] + s_red[1][1] + s_red[2][1] + s_red[3][1]);
  }
}

// ============ loc loss: one wave per batch, last-valid-m-wins dedup ============
__global__ __launch_bounds__(64) void loss_B(
    const float* __restrict__ pred, const float* __restrict__ targ,
    const float* __restrict__ anch, const unsigned long long* __restrict__ keys,
    float* __restrict__ accum) {
  const int b = blockIdx.x;
  const int m = threadIdx.x;  // one wave; lanes 0..29 carry GTs
  int idx = -1;
  int valid = 0;
  float t0 = 0.f, t1 = 0.f, t2 = 0.f, t3 = 0.f;
  if (m < kM) {
    const unsigned long long k = keys[b * kM + m];
    idx = (k == 0ull) ? 0 : (int)(0xFFFFFFFFu - (unsigned)(k & 0xFFFFFFFFull));
    t0 = targ[b * kM * 5 + m * 5 + 0];
    t1 = targ[b * kM * 5 + m * 5 + 1];
    t2 = targ[b * kM * 5 + m * 5 + 2];
    t3 = targ[b * kM * 5 + m * 5 + 3];
    valid = (targ[b * kM * 5 + m * 5 + 4] == 1.0f) ? 1 : 0;
  }
  // last-valid-m-wins dedup (matches scatter overwrite order)
  bool dead = false;
  for (int j = 1; j < kM; ++j) {
    const int idx2 = __shfl(idx, j);
    const int v2 = __shfl(valid, j);
    if (j > m && v2 && idx2 == idx) dead = true;
  }
  float loc = 0.0f;
  if (m < kM && valid && !dead) {
    const float gxc = t0 + t2 * 0.5f;
    const float gyc = t1 + t3 * 0.5f;
    const int ra = idx % kA;
    const int rw = (idx / kA) % kS;
    const int rh = idx / (kA * kS);
    const float tx = (gxc - (float)rw * kCW) / kCW;
    const float ty = (gyc - (float)rh * kCW) / kCW;
    const float tw = logf((t2 / kCW) / anch[2 * ra + 0]);
    const float th = logf((t3 / kCW) / anch[2 * ra + 1]);
    const float* pp = pred + ((size_t)b * kP + idx) * 25;
    const float d0 = sig(pp[0]) - tx;
    const float d1 = sig(pp[1]) - ty;
    const float d2 = sig(pp[2]) * 0.5f - tw;
    const float d3 = sig(pp[3]) * 0.5f - th;
    loc = d0 * d0 + d1 * d1 + d2 * d2 + d3 * d3;
  }
  loc = wave_sum(loc);
  if (m == 0) atomicAdd(&accum[2], loc);
}

__global__ void loss_C(const float* __restrict__ accum, float* __restrict__ out) {
  if (threadIdx.x == 0) {
    const float loss_conf = (accum[0] + 0.5f * accum[1]) / (float)kB;
    const float loss_loc = 5.0f * accum[2] / (float)kB;
    out[0] = loss_loc + loss_conf;
    out[1] = loss_loc;
    out[2] = loss_conf;
  }
}

}  // namespace

extern "C" void kernel_launch(void* const* d_in, const int* in_sizes, int n_in,
                              void* d_out, int out_size, void* d_ws, size_t ws_size,
                              hipStream_t stream) {
  const float* pred = (const float*)d_in[0];
  const float* targ = (const float*)d_in[1];
  const float* anch = (const float*)d_in[2];
  float* out = (float*)d_out;
  unsigned long long* keys = (unsigned long long*)d_ws;
  float* accum = (float*)((char*)d_ws + kKeyBytes);

  hipMemsetAsync(d_ws, 0, kZeroBytes, stream);
  yolo_main<<<dim3(kChunks, kB), kT, 0, stream>>>(pred, targ, anch, keys, accum);
  loss_B<<<kB, 64, 0, stream>>>(pred, targ, anch, keys, accum);
  loss_C<<<1, 64, 0, stream>>>(accum, out);
}